// Round 9
// baseline (150.483 us; speedup 1.0000x reference)
//
#include <hip/hip_runtime.h>

// MoE top-2 of 3x3 SAME convs via bf16 MFMA implicit GEMM.
//
// R15: L2-TRAFFIC reduction (2.5x). R9/R11/R14 all ~43-47us regardless of
// pipelining discipline => not latency-bound; L2->CU path is saturated:
// 7 blocks/CU x (288KB B + 72KB A) = 2.5MB/CU at 25-55 B/cy = the whole
// 110k-cy envelope. Kill duplication instead of hiding it:
//  1. r-overlap dedup: load the 6 input rows ONCE per (s,ks) group into
//     regs (bfb[2][6]); iterate r INSIDE, reusing frags across r (72->36
//     B-loads/wave).
//  2. Merge the mh CO-split back (acc 128, 896 blocks): both halves read
//     identical B; merging halves per-output B-traffic again.
// Per block now: A 144KB + B 144KB for 2x the output => per-CU 1.0MB.
// Pipeline: 6 groups g=(s,ks); {stage 24KB A (6 gll/wave) + 6 asm B-loads}
// issued AFTER the group barrier (prev readers done => no WAR race),
// consumed next group; 96-MFMA cluster (~470cy) covers them; one fully-
// covered vmcnt(0) per group.
// Predicted: VGPR ~210-230 (WRITE>53MB = spills = abort), main 46->24-32us,
// MfmaUtil 27->~50%, FETCH ~18MB flat, total ~120-130us.

#define BB 64
#define CC 64
#define COO 64
#define HH 56
#define WW 56

typedef __bf16 bf16x8 __attribute__((ext_vector_type(8)));
typedef float  f32x4  __attribute__((ext_vector_type(4)));

// ---- prep: fused transpose (fat blocks) + weight pack (unchanged) ----------
__global__ __launch_bounds__(256) void prep_kernel(
    const float* __restrict__ x, const float* __restrict__ Wexp,
    __bf16* __restrict__ xT, __bf16* __restrict__ Wpack)
{
    const int bx  = blockIdx.x;
    const int tid = threadIdx.x;

    if (bx < 960) {
        // Output row layout: [cg 8][wc 66][8 c] (c-octet-major), 4224 bf16/row.
        __shared__ float tile[CC][WW + 1];   // stride 57: reads 2-way max
        const int b   = bx / 15;
        const int grp = bx - b * 15;         // 0..14 -> hp = grp*4 + rr
        #pragma unroll 1
        for (int rr = 0; rr < 4; ++rr) {
            const int hp = grp * 4 + rr;
            if (hp >= 58) break;
            __bf16* dst = xT + ((size_t)b * 58 + hp) * 4224;
            const bool interior = (hp >= 1 && hp <= HH);
            if (!interior) {                 // pad row: zero-fill (no LDS use)
                bf16x8 z = {};
                for (int j = tid; j < 4224 / 8; j += 256)
                    *(bf16x8*)(dst + j * 8) = z;
                continue;                    // hp uniform per block: no diverge
            }
            const int h = hp - 1;
            const float* xb = x + (size_t)b * CC * HH * WW + (size_t)h * WW;
            for (int i = tid; i < CC * 14; i += 256) {
                const int c = i / 14, wq = i - c * 14;
                const float4 f = *(const float4*)(xb + (size_t)c * HH * WW + wq * 4);
                tile[c][wq * 4 + 0] = f.x; tile[c][wq * 4 + 1] = f.y;
                tile[c][wq * 4 + 2] = f.z; tile[c][wq * 4 + 3] = f.w;
            }
            __syncthreads();
            for (int j = tid; j < 66 * 8; j += 256) {
                const int cg = j / 66;           // c-octet 0..7
                const int wc = j - cg * 66;      // padded col 0..65
                bf16x8 v = {};
                if (wc >= 1 && wc <= WW) {
                    const int w = wc - 1;
                    #pragma unroll
                    for (int u = 0; u < 8; ++u)
                        v[u] = (__bf16)tile[cg * 8 + u][w];
                }
                *(bf16x8*)(dst + j * 8) = v;     // 16B coalesced (j-linear)
            }
            __syncthreads();                 // before next rr reuses tile
        }
    } else {
        // Wpack[e*36864 + rs*4096 + ks*2048 + mt*512 + lane*8 + j]
        //   = bf16( Wexp[e][mt*16+(lane&15)][ks*32+(lane>>4)*8+j][r][s] )
        const int wp = bx - 960;             // 0..71
        const int e  = wp / 9, rs = wp - e * 9;
        const int r  = rs / 3, s  = rs - r * 3;
        for (int idx = tid; idx < 4096; idx += 256) {
            const int ks   = idx >> 11;
            const int rem  = idx & 2047;
            const int mt   = rem >> 9;
            const int lane = (rem >> 3) & 63;
            const int j    = idx & 7;
            const int co = mt * 16 + (lane & 15);
            const int c  = ks * 32 + ((lane >> 4) << 3) + j;
            const float v = Wexp[((((size_t)e * COO + co) * CC + c) * 3 + r) * 3 + s];
            Wpack[(size_t)e * 36864 + (size_t)rs * 4096 + idx] = (__bf16)v;
        }
    }
}

// ---- Main: full-CO blocks, 6 (s,ks) groups, B-dedup via r-inner reuse ------
__global__ __launch_bounds__(256, 2) void moe_conv_mfma(
    const __bf16* __restrict__ xT, const __bf16* __restrict__ Wpack,
    const float* __restrict__ gate_w, const int* __restrict__ gate_i,
    const float* __restrict__ bexp, float* __restrict__ out)
{
    __shared__ __align__(16) __bf16 ldsA[2 * 12288];  // 2 bufs x 24KB = 48KB

    // 896 blocks; XCD swizzle: 112 consecutive swz per XCD = 8 samples.
    const int bid = blockIdx.x;
    const int swz = (bid & 7) * 112 + (bid >> 3);
    const int b   = swz / 14;
    const int h0  = (swz - b * 14) * 4;  // output rows h0..h0+3

    const int tid = threadIdx.x;
    const int wid = tid >> 6, lane = tid & 63;
    const int n15 = lane & 15, quad = lane >> 4;
    const int wcol = wid * 16 + n15;    // padded col 0..63

    const int   e0 = gate_i[b * 2 + 0], e1 = gate_i[b * 2 + 1];
    const float g0 = gate_w[b * 2 + 0], g1 = gate_w[b * 2 + 1];
    const __bf16* w0 = Wpack + (size_t)e0 * 36864;
    const __bf16* w1 = Wpack + (size_t)e1 * 36864;

    // Stage group g=(s,ks): 24 chunks (r3 x slot2 x mt4) x 1KB; wave wid
    // does 6. chunk ch = r*8 + slot*4 + mt; dest = uniform base + lane*16B.
    auto stage = [&](int g, int bufn) {
        const int s = g >> 1, ks = g & 1;
        #pragma unroll
        for (int i = 0; i < 6; ++i) {
            const int ch = wid * 6 + i;          // 0..23
            const int r = ch >> 3, rm = ch & 7;
            const int slot = rm >> 2, mt = rm & 3;
            const __bf16* src = (slot ? w1 : w0) + (size_t)(r * 3 + s) * 4096
                              + ks * 2048 + mt * 512 + lane * 8;
            __bf16* dstp = &ldsA[bufn * 12288 + ch * 512 + lane * 8];
            __builtin_amdgcn_global_load_lds(
                (const __attribute__((address_space(1))) unsigned int*)src,
                (__attribute__((address_space(3))) unsigned int*)dstp, 16, 0, 0);
        }
    };

    // xT strides (bf16): b 244992, hp 4224, cg 528 (cg = ks*4 + quad).
    const __bf16* pqh = xT + (size_t)b * 244992 + (size_t)h0 * 4224
                      + quad * 528 + wcol * 8;

    f32x4 acc[2][4][4] = {};            // [slot][mt][t] = 128 VGPRs
    f32x4 bfb[2][6];                    // [buf][hp offset 0..5] = 48 VGPRs

    // Issue the 6 deduped B-row loads for group g (rows h0..h0+5 at wc=
    // wcol+s, ks-half): volatile asm = unmovable, results forcibly live.
    auto issueB = [&](int g, int bufn) {
        const int s = g >> 1, ks = g & 1;
        #pragma unroll
        for (int t = 0; t < 6; ++t) {
            const __bf16* a = pqh + (size_t)t * 4224 + s * 8 + ks * 2112;
            asm volatile("global_load_dwordx4 %0, %1, off"
                         : "=&v"(bfb[bufn][t]) : "v"(a));
        }
    };

    // Prologue: issue G0 (12 vm-ops). Each group's loads are consumed one
    // group later, covered by the current group's 96-MFMA cluster.
    stage(0, 0);
    issueB(0, 0);

    #pragma unroll
    for (int g = 0; g < 6; ++g) {
        const int buf = g & 1;
        // G(g) complete (issued one group ago; covered by G(g-1) compute).
        asm volatile("s_waitcnt vmcnt(0)" ::: "memory");
        __builtin_amdgcn_sched_barrier(0);
        __builtin_amdgcn_s_barrier();   // all waves' stage(g) writes landed
        __builtin_amdgcn_sched_barrier(0);
        // Issue G(g+1) AFTER the barrier: buf^1's readers (compute G(g-1))
        // finished before it => no WAR race on the LDS buffer.
        if (g < 5) { stage(g + 1, buf ^ 1); issueB(g + 1, buf ^ 1); }
        __builtin_amdgcn_sched_barrier(0);

        __builtin_amdgcn_s_setprio(1);
        #pragma unroll
        for (int r = 0; r < 3; ++r) {
            #pragma unroll
            for (int slot = 0; slot < 2; ++slot) {
                #pragma unroll
                for (int mt = 0; mt < 4; ++mt) {
                    const bf16x8 af = *(const bf16x8*)
                        &ldsA[buf * 12288 + (r * 8 + slot * 4 + mt) * 512
                              + lane * 8];
                    #pragma unroll
                    for (int t = 0; t < 4; ++t)
                        acc[slot][mt][t] = __builtin_amdgcn_mfma_f32_16x16x32_bf16(
                            af, __builtin_bit_cast(bf16x8, bfb[buf][r + t]),
                            acc[slot][mt][t], 0, 0, 0);
                }
            }
        }
        __builtin_amdgcn_s_setprio(0);
    }

    // Epilogue: D layout col=lane&15 (pixel), row=quad*4+reg (co within mt).
    if (wcol < WW) {
        #pragma unroll
        for (int t = 0; t < 4; ++t) {
            const int h = h0 + t;
            #pragma unroll
            for (int mt = 0; mt < 4; ++mt) {
                #pragma unroll
                for (int v = 0; v < 4; ++v) {
                    const int co = mt * 16 + quad * 4 + v;
                    float a0 = acc[0][mt][t][v] + bexp[e0 * COO + co];
                    float a1 = acc[1][mt][t][v] + bexp[e1 * COO + co];
                    a0 = fmaxf(a0, 0.f);
                    a1 = fmaxf(a1, 0.f);
                    out[(((size_t)b * COO + co) * HH + h) * WW + wcol] =
                        g0 * a0 + g1 * a1;
                }
            }
        }
    }
}

extern "C" void kernel_launch(void* const* d_in, const int* in_sizes, int n_in,
                              void* d_out, int out_size, void* d_ws, size_t ws_size,
                              hipStream_t stream) {
    const float* x      = (const float*)d_in[0];
    const float* gate_w = (const float*)d_in[1];
    const int*   gate_i = (const int*)  d_in[2];
    const float* Wexp   = (const float*)d_in[3];
    const float* bexp   = (const float*)d_in[4];
    float* out = (float*)d_out;

    // Wpack first (fixed 589,824 B, 16B-aligned), then xT (31,358,976 B).
    __bf16* Wpack = (__bf16*)d_ws;
    __bf16* xT    = (__bf16*)((char*)d_ws + 589824);

    prep_kernel<<<dim3(1032), 256, 0, stream>>>(x, Wexp, xT, Wpack);
    moe_conv_mfma<<<dim3(896), 256, 0, stream>>>(xT, Wpack, gate_w, gate_i,
                                                 bexp, out);
}

// Round 11
// 144.896 us; speedup vs baseline: 1.0386x; 1.0386x over previous
//
#include <hip/hip_runtime.h>

// MoE top-2 of 3x3 SAME convs via bf16 MFMA implicit GEMM.
//
// R17 = R16 hardened resubmit (3rd "container failed twice"; R8/R13
// precedents both passed on resubmit). De-risk: drop R16's only novel
// construct (global_load_lds into f32 tile from a strided loop in prep) and
// use the proven reg-staged float4->LDS path instead; prep experiment
// otherwise intact, main = R15 verbatim.
//
// R16 rationale (unchanged): R15 showed main is pinned at ~44us across 4
// orthogonal structural changes (drains/pins/counted-pipeline/traffic-cut)
// => structural envelope; attack the unmeasured prep slice instead.
// Old prep: 960 fat blocks, 8 barriers each => suspected ~2 TB/s ~40us.
// New prep: 1 block per (b,hp) row (3712 + 72 wpack blocks), ONE barrier,
// float4 reads -> linear f32 LDS tile (16B/lane consecutive = conflict-
// free) -> 8 strided reads -> bf16x8 coalesced stores. Pad rows pure
// zero-fill.
// Predicted: main identical (44-45us, FETCH ~18.6MB, WRITE ~50.7MB); prep
// ~20-27us; total 150.5 -> ~128-138us (flat ~148 => prep was already fast
// => controllable floor reached).

#define BB 64
#define CC 64
#define COO 64
#define HH 56
#define WW 56

typedef __bf16 bf16x8 __attribute__((ext_vector_type(8)));
typedef float  f32x4  __attribute__((ext_vector_type(4)));

// ---- prep: thin-block transpose (1 barrier) + weight pack ------------------
__global__ __launch_bounds__(256) void prep_kernel(
    const float* __restrict__ x, const float* __restrict__ Wexp,
    __bf16* __restrict__ xT, __bf16* __restrict__ Wpack)
{
    const int bx  = blockIdx.x;
    const int tid = threadIdx.x;

    if (bx < 3712) {
        // ---- xpose: block = one padded row (b, hp) -------------------------
        // Output row layout: [cg 8][wc 66][8 c] (c-octet-major), 4224 bf16.
        const int b  = bx / 58;
        const int hp = bx - b * 58;
        __bf16* dst = xT + ((size_t)b * 58 + hp) * 4224;

        if (hp == 0 || hp == 57) {           // pad row: zero-fill, no LDS
            bf16x8 z = {};
            for (int j = tid; j < 528; j += 256)
                *(bf16x8*)(dst + j * 8) = z;
            return;
        }

        __shared__ __align__(16) float tile[CC * WW];   // [c][w] linear, 14.3KB
        const int h = hp - 1;
        const float* xb = x + ((size_t)b * CC * HH + h) * WW;  // + c*HH*WW

        // 896 16B chunks: chunk i = c*14 + wq -> tile[i*4 .. i*4+3].
        // Reg-staged (proven pattern): float4 load -> f32x4 LDS write;
        // per-lane 16B consecutive => conflict-free ds_write_b128.
        for (int i = tid; i < 896; i += 256) {
            const int c = i / 14, wq = i - c * 14;
            const f32x4 f = *(const f32x4*)(xb + (size_t)c * (HH * WW) + wq * 4);
            *(f32x4*)&tile[i * 4] = f;
        }
        __syncthreads();                     // the ONLY barrier

        // Transpose-write: j = cg*66 + wc; 16B coalesced stores.
        for (int j = tid; j < 528; j += 256) {
            const int cg = j / 66, wc = j - cg * 66;
            bf16x8 v = {};
            if (wc >= 1 && wc <= WW) {
                #pragma unroll
                for (int u = 0; u < 8; ++u)
                    v[u] = (__bf16)tile[(cg * 8 + u) * WW + (wc - 1)];
            }
            *(bf16x8*)(dst + j * 8) = v;
        }
    } else {
        // ---- wpack part (verified R3+ body) --------------------------------
        // Wpack[e*36864 + rs*4096 + ks*2048 + mt*512 + lane*8 + j]
        //   = bf16( Wexp[e][mt*16+(lane&15)][ks*32+(lane>>4)*8+j][r][s] )
        const int wp = bx - 3712;            // 0..71
        const int e  = wp / 9, rs = wp - e * 9;
        const int r  = rs / 3, s  = rs - r * 3;
        for (int idx = tid; idx < 4096; idx += 256) {
            const int ks   = idx >> 11;
            const int rem  = idx & 2047;
            const int mt   = rem >> 9;
            const int lane = (rem >> 3) & 63;
            const int j    = idx & 7;
            const int co = mt * 16 + (lane & 15);
            const int c  = ks * 32 + ((lane >> 4) << 3) + j;
            const float v = Wexp[((((size_t)e * COO + co) * CC + c) * 3 + r) * 3 + s];
            Wpack[(size_t)e * 36864 + (size_t)rs * 4096 + idx] = (__bf16)v;
        }
    }
}

// ---- Main: full-CO blocks, 6 (s,ks) groups, B-dedup (R15 verbatim) ---------
__global__ __launch_bounds__(256, 2) void moe_conv_mfma(
    const __bf16* __restrict__ xT, const __bf16* __restrict__ Wpack,
    const float* __restrict__ gate_w, const int* __restrict__ gate_i,
    const float* __restrict__ bexp, float* __restrict__ out)
{
    __shared__ __align__(16) __bf16 ldsA[2 * 12288];  // 2 bufs x 24KB = 48KB

    // 896 blocks; XCD swizzle: 112 consecutive swz per XCD = 8 samples.
    const int bid = blockIdx.x;
    const int swz = (bid & 7) * 112 + (bid >> 3);
    const int b   = swz / 14;
    const int h0  = (swz - b * 14) * 4;  // output rows h0..h0+3

    const int tid = threadIdx.x;
    const int wid = tid >> 6, lane = tid & 63;
    const int n15 = lane & 15, quad = lane >> 4;
    const int wcol = wid * 16 + n15;    // padded col 0..63

    const int   e0 = gate_i[b * 2 + 0], e1 = gate_i[b * 2 + 1];
    const float g0 = gate_w[b * 2 + 0], g1 = gate_w[b * 2 + 1];
    const __bf16* w0 = Wpack + (size_t)e0 * 36864;
    const __bf16* w1 = Wpack + (size_t)e1 * 36864;

    // Stage group g=(s,ks): 24 chunks (r3 x slot2 x mt4) x 1KB; wave wid
    // does 6. chunk ch = r*8 + slot*4 + mt; dest = uniform base + lane*16B.
    auto stage = [&](int g, int bufn) {
        const int s = g >> 1, ks = g & 1;
        #pragma unroll
        for (int i = 0; i < 6; ++i) {
            const int ch = wid * 6 + i;          // 0..23
            const int r = ch >> 3, rm = ch & 7;
            const int slot = rm >> 2, mt = rm & 3;
            const __bf16* src = (slot ? w1 : w0) + (size_t)(r * 3 + s) * 4096
                              + ks * 2048 + mt * 512 + lane * 8;
            __bf16* dstp = &ldsA[bufn * 12288 + ch * 512 + lane * 8];
            __builtin_amdgcn_global_load_lds(
                (const __attribute__((address_space(1))) unsigned int*)src,
                (__attribute__((address_space(3))) unsigned int*)dstp, 16, 0, 0);
        }
    };

    // xT strides (bf16): b 244992, hp 4224, cg 528 (cg = ks*4 + quad).
    const __bf16* pqh = xT + (size_t)b * 244992 + (size_t)h0 * 4224
                      + quad * 528 + wcol * 8;

    f32x4 acc[2][4][4] = {};            // [slot][mt][t] = 128 VGPRs
    f32x4 bfb[2][6];                    // [buf][hp offset 0..5] = 48 VGPRs

    // Issue the 6 deduped B-row loads for group g (rows h0..h0+5 at wc=
    // wcol+s, ks-half): volatile asm = unmovable, results forcibly live.
    auto issueB = [&](int g, int bufn) {
        const int s = g >> 1, ks = g & 1;
        #pragma unroll
        for (int t = 0; t < 6; ++t) {
            const __bf16* a = pqh + (size_t)t * 4224 + s * 8 + ks * 2112;
            asm volatile("global_load_dwordx4 %0, %1, off"
                         : "=&v"(bfb[bufn][t]) : "v"(a));
        }
    };

    // Prologue: issue G0 (12 vm-ops). Each group's loads are consumed one
    // group later, covered by the current group's 96-MFMA cluster.
    stage(0, 0);
    issueB(0, 0);

    #pragma unroll
    for (int g = 0; g < 6; ++g) {
        const int buf = g & 1;
        // G(g) complete (issued one group ago; covered by G(g-1) compute).
        asm volatile("s_waitcnt vmcnt(0)" ::: "memory");
        __builtin_amdgcn_sched_barrier(0);
        __builtin_amdgcn_s_barrier();   // all waves' stage(g) writes landed
        __builtin_amdgcn_sched_barrier(0);
        // Issue G(g+1) AFTER the barrier: buf^1's readers (compute G(g-1))
        // finished before it => no WAR race on the LDS buffer.
        if (g < 5) { stage(g + 1, buf ^ 1); issueB(g + 1, buf ^ 1); }
        __builtin_amdgcn_sched_barrier(0);

        __builtin_amdgcn_s_setprio(1);
        #pragma unroll
        for (int r = 0; r < 3; ++r) {
            #pragma unroll
            for (int slot = 0; slot < 2; ++slot) {
                #pragma unroll
                for (int mt = 0; mt < 4; ++mt) {
                    const bf16x8 af = *(const bf16x8*)
                        &ldsA[buf * 12288 + (r * 8 + slot * 4 + mt) * 512
                              + lane * 8];
                    #pragma unroll
                    for (int t = 0; t < 4; ++t)
                        acc[slot][mt][t] = __builtin_amdgcn_mfma_f32_16x16x32_bf16(
                            af, __builtin_bit_cast(bf16x8, bfb[buf][r + t]),
                            acc[slot][mt][t], 0, 0, 0);
                }
            }
        }
        __builtin_amdgcn_s_setprio(0);
    }

    // Epilogue: D layout col=lane&15 (pixel), row=quad*4+reg (co within mt).
    if (wcol < WW) {
        #pragma unroll
        for (int t = 0; t < 4; ++t) {
            const int h = h0 + t;
            #pragma unroll
            for (int mt = 0; mt < 4; ++mt) {
                #pragma unroll
                for (int v = 0; v < 4; ++v) {
                    const int co = mt * 16 + quad * 4 + v;
                    float a0 = acc[0][mt][t][v] + bexp[e0 * COO + co];
                    float a1 = acc[1][mt][t][v] + bexp[e1 * COO + co];
                    a0 = fmaxf(a0, 0.f);
                    a1 = fmaxf(a1, 0.f);
                    out[(((size_t)b * COO + co) * HH + h) * WW + wcol] =
                        g0 * a0 + g1 * a1;
                }
            }
        }
    }
}

extern "C" void kernel_launch(void* const* d_in, const int* in_sizes, int n_in,
                              void* d_out, int out_size, void* d_ws, size_t ws_size,
                              hipStream_t stream) {
    const float* x      = (const float*)d_in[0];
    const float* gate_w = (const float*)d_in[1];
    const int*   gate_i = (const int*)  d_in[2];
    const float* Wexp   = (const float*)d_in[3];
    const float* bexp   = (const float*)d_in[4];
    float* out = (float*)d_out;

    // Wpack first (fixed 589,824 B, 16B-aligned), then xT (31,358,976 B).
    __bf16* Wpack = (__bf16*)d_ws;
    __bf16* xT    = (__bf16*)((char*)d_ws + 589824);

    prep_kernel<<<dim3(3784), 256, 0, stream>>>(x, Wexp, xT, Wpack);
    moe_conv_mfma<<<dim3(896), 256, 0, stream>>>(xT, Wpack, gate_w, gate_i,
                                                 bexp, out);
}

// Round 12
// 140.532 us; speedup vs baseline: 1.0708x; 1.0311x over previous
//
#include <hip/hip_runtime.h>

// MoE top-2 of 3x3 SAME convs via bf16 MFMA implicit GEMM.
//
// R18 = R15 group-dedup structure x R9 mh-split geometry (occupancy play).
// R17 post-mortem: prep ~15-17us (near BW floor), main pinned 43us with
// true mfma-busy ~10%, HBM 20%, Occupancy 15% (~1.2-1.5 blocks/CU) --
// latency-bound with too few waves. R15's de-split halved the grid and
// doubled per-block state for a traffic cut that R15 itself proved
// non-binding. Revert that trade, keep the group pipeline:
//  - CO re-split (mh): acc 64 VGPR, group A = 12KB, LDS dbuf 24KB,
//    grid 1792 (7/CU, R9's proven bijective XCD swizzle).
//  - VGPR ~137 w/ launch_bounds(256,3) -> 3 blocks/CU resident (~2.4x
//    measured residency). B rows re-read by both mh halves: +~1-2us of
//    non-binding traffic.
//  - Group pipeline verbatim R15: volatile-asm B prefetch one group ahead,
//    stage-after-barrier, single vmcnt(0)/group covered by 48 MFMAs,
//    setprio around the MFMA cluster. Prep = R17 verbatim (passed).
// Predicted: Occ 15->30-40%, main 43->30-35us, FETCH ~21-24MB, WRITE flat,
// total ~132-137us. Flat main despite 2x occupancy => floor call next.

#define BB 64
#define CC 64
#define COO 64
#define HH 56
#define WW 56

typedef __bf16 bf16x8 __attribute__((ext_vector_type(8)));
typedef float  f32x4  __attribute__((ext_vector_type(4)));

// ---- prep: thin-block transpose (1 barrier) + weight pack (R17 verbatim) ---
__global__ __launch_bounds__(256) void prep_kernel(
    const float* __restrict__ x, const float* __restrict__ Wexp,
    __bf16* __restrict__ xT, __bf16* __restrict__ Wpack)
{
    const int bx  = blockIdx.x;
    const int tid = threadIdx.x;

    if (bx < 3712) {
        // ---- xpose: block = one padded row (b, hp) -------------------------
        // Output row layout: [cg 8][wc 66][8 c] (c-octet-major), 4224 bf16.
        const int b  = bx / 58;
        const int hp = bx - b * 58;
        __bf16* dst = xT + ((size_t)b * 58 + hp) * 4224;

        if (hp == 0 || hp == 57) {           // pad row: zero-fill, no LDS
            bf16x8 z = {};
            for (int j = tid; j < 528; j += 256)
                *(bf16x8*)(dst + j * 8) = z;
            return;
        }

        __shared__ __align__(16) float tile[CC * WW];   // [c][w] linear, 14.3KB
        const int h = hp - 1;
        const float* xb = x + ((size_t)b * CC * HH + h) * WW;  // + c*HH*WW

        // 896 16B chunks: chunk i = c*14 + wq -> tile[i*4 .. i*4+3].
        // Reg-staged: float4 load -> f32x4 LDS write (conflict-free b128).
        for (int i = tid; i < 896; i += 256) {
            const int c = i / 14, wq = i - c * 14;
            const f32x4 f = *(const f32x4*)(xb + (size_t)c * (HH * WW) + wq * 4);
            *(f32x4*)&tile[i * 4] = f;
        }
        __syncthreads();                     // the ONLY barrier

        // Transpose-write: j = cg*66 + wc; 16B coalesced stores.
        for (int j = tid; j < 528; j += 256) {
            const int cg = j / 66, wc = j - cg * 66;
            bf16x8 v = {};
            if (wc >= 1 && wc <= WW) {
                #pragma unroll
                for (int u = 0; u < 8; ++u)
                    v[u] = (__bf16)tile[(cg * 8 + u) * WW + (wc - 1)];
            }
            *(bf16x8*)(dst + j * 8) = v;
        }
    } else {
        // ---- wpack part (verified R3+ body) --------------------------------
        // Wpack[e*36864 + rs*4096 + ks*2048 + mt*512 + lane*8 + j]
        //   = bf16( Wexp[e][mt*16+(lane&15)][ks*32+(lane>>4)*8+j][r][s] )
        const int wp = bx - 3712;            // 0..71
        const int e  = wp / 9, rs = wp - e * 9;
        const int r  = rs / 3, s  = rs - r * 3;
        for (int idx = tid; idx < 4096; idx += 256) {
            const int ks   = idx >> 11;
            const int rem  = idx & 2047;
            const int mt   = rem >> 9;
            const int lane = (rem >> 3) & 63;
            const int j    = idx & 7;
            const int co = mt * 16 + (lane & 15);
            const int c  = ks * 32 + ((lane >> 4) << 3) + j;
            const float v = Wexp[((((size_t)e * COO + co) * CC + c) * 3 + r) * 3 + s];
            Wpack[(size_t)e * 36864 + (size_t)rs * 4096 + idx] = (__bf16)v;
        }
    }
}

// ---- Main: CO-split blocks, 6 (s,ks) groups, B-dedup, 24KB LDS dbuf --------
__global__ __launch_bounds__(256, 3) void moe_conv_mfma(
    const __bf16* __restrict__ xT, const __bf16* __restrict__ Wpack,
    const float* __restrict__ gate_w, const int* __restrict__ gate_i,
    const float* __restrict__ bexp, float* __restrict__ out)
{
    __shared__ __align__(16) __bf16 ldsA[2 * 6144];  // 2 bufs x 12KB = 24KB

    // XCD swizzle: 1792 blocks, 224 consecutive swz per XCD (= 8 samples).
    const int bid = blockIdx.x;
    const int swz = (bid & 7) * 224 + (bid >> 3);
    const int b   = swz / 28;
    const int rem = swz - b * 28;
    const int h0  = (rem >> 1) * 4;     // output rows h0..h0+3
    const int mh  = rem & 1;            // CO half: mt = mh*2 + mtl

    const int tid = threadIdx.x;
    const int wid = tid >> 6, lane = tid & 63;
    const int n15 = lane & 15, quad = lane >> 4;
    const int wcol = wid * 16 + n15;    // padded col 0..63

    const int   e0 = gate_i[b * 2 + 0], e1 = gate_i[b * 2 + 1];
    const float g0 = gate_w[b * 2 + 0], g1 = gate_w[b * 2 + 1];
    const __bf16* w0 = Wpack + (size_t)e0 * 36864;
    const __bf16* w1 = Wpack + (size_t)e1 * 36864;

    // Stage group g=(s,ks): 12 chunks (r3 x slot2 x mtl2) x 1KB; wave wid
    // does 3. ch = wid*3+i = r*4 + slot*2 + mtl; dest = uniform + lane*16B.
    auto stage = [&](int g, int bufn) {
        const int s = g >> 1, ks = g & 1;
        #pragma unroll
        for (int i = 0; i < 3; ++i) {
            const int ch = wid * 3 + i;          // 0..11
            const int r = ch >> 2, rm = ch & 3;
            const int slot = rm >> 1, mtl = rm & 1;
            const __bf16* src = (slot ? w1 : w0) + (size_t)(r * 3 + s) * 4096
                              + ks * 2048 + (mh * 2 + mtl) * 512 + lane * 8;
            __bf16* dstp = &ldsA[bufn * 6144 + ch * 512 + lane * 8];
            __builtin_amdgcn_global_load_lds(
                (const __attribute__((address_space(1))) unsigned int*)src,
                (__attribute__((address_space(3))) unsigned int*)dstp, 16, 0, 0);
        }
    };

    // xT strides (bf16): b 244992, hp 4224, cg 528 (cg = ks*4 + quad).
    const __bf16* pqh = xT + (size_t)b * 244992 + (size_t)h0 * 4224
                      + quad * 528 + wcol * 8;

    f32x4 acc[2][2][4] = {};            // [slot][mtl][t] = 64 VGPRs
    f32x4 bfb[2][6];                    // [buf][hp offset 0..5] = 48 VGPRs

    // Issue the 6 deduped B-row loads for group g (rows h0..h0+5 at wc=
    // wcol+s, ks-half): volatile asm = unmovable, results forcibly live.
    auto issueB = [&](int g, int bufn) {
        const int s = g >> 1, ks = g & 1;
        #pragma unroll
        for (int t = 0; t < 6; ++t) {
            const __bf16* a = pqh + (size_t)t * 4224 + s * 8 + ks * 2112;
            asm volatile("global_load_dwordx4 %0, %1, off"
                         : "=&v"(bfb[bufn][t]) : "v"(a));
        }
    };

    // Prologue: issue G0 (9 vm-ops/wave). Each group's loads are consumed
    // one group later, covered by the current group's 48-MFMA cluster.
    stage(0, 0);
    issueB(0, 0);

    #pragma unroll
    for (int g = 0; g < 6; ++g) {
        const int buf = g & 1;
        // G(g) complete (issued one group ago; covered by G(g-1) compute).
        asm volatile("s_waitcnt vmcnt(0)" ::: "memory");
        __builtin_amdgcn_sched_barrier(0);
        __builtin_amdgcn_s_barrier();   // all waves' stage(g) writes landed
        __builtin_amdgcn_sched_barrier(0);
        // Issue G(g+1) AFTER the barrier: buf^1's readers (compute G(g-1))
        // finished before it => no WAR race on the LDS buffer.
        if (g < 5) { stage(g + 1, buf ^ 1); issueB(g + 1, buf ^ 1); }
        __builtin_amdgcn_sched_barrier(0);

        __builtin_amdgcn_s_setprio(1);
        #pragma unroll
        for (int r = 0; r < 3; ++r) {
            #pragma unroll
            for (int slot = 0; slot < 2; ++slot) {
                #pragma unroll
                for (int mtl = 0; mtl < 2; ++mtl) {
                    const bf16x8 af = *(const bf16x8*)
                        &ldsA[buf * 6144 + (r * 4 + slot * 2 + mtl) * 512
                              + lane * 8];
                    #pragma unroll
                    for (int t = 0; t < 4; ++t)
                        acc[slot][mtl][t] = __builtin_amdgcn_mfma_f32_16x16x32_bf16(
                            af, __builtin_bit_cast(bf16x8, bfb[buf][r + t]),
                            acc[slot][mtl][t], 0, 0, 0);
                }
            }
        }
        __builtin_amdgcn_s_setprio(0);
    }

    // Epilogue: D layout col=lane&15 (pixel), row=quad*4+reg (co within mt).
    if (wcol < WW) {
        #pragma unroll
        for (int t = 0; t < 4; ++t) {
            const int h = h0 + t;
            #pragma unroll
            for (int mtl = 0; mtl < 2; ++mtl) {
                #pragma unroll
                for (int v = 0; v < 4; ++v) {
                    const int co = (mh * 2 + mtl) * 16 + quad * 4 + v;
                    float a0 = acc[0][mtl][t][v] + bexp[e0 * COO + co];
                    float a1 = acc[1][mtl][t][v] + bexp[e1 * COO + co];
                    a0 = fmaxf(a0, 0.f);
                    a1 = fmaxf(a1, 0.f);
                    out[(((size_t)b * COO + co) * HH + h) * WW + wcol] =
                        g0 * a0 + g1 * a1;
                }
            }
        }
    }
}

extern "C" void kernel_launch(void* const* d_in, const int* in_sizes, int n_in,
                              void* d_out, int out_size, void* d_ws, size_t ws_size,
                              hipStream_t stream) {
    const float* x      = (const float*)d_in[0];
    const float* gate_w = (const float*)d_in[1];
    const int*   gate_i = (const int*)  d_in[2];
    const float* Wexp   = (const float*)d_in[3];
    const float* bexp   = (const float*)d_in[4];
    float* out = (float*)d_out;

    // Wpack first (fixed 589,824 B, 16B-aligned), then xT (31,358,976 B).
    __bf16* Wpack = (__bf16*)d_ws;
    __bf16* xT    = (__bf16*)((char*)d_ws + 589824);

    prep_kernel<<<dim3(3784), 256, 0, stream>>>(x, Wexp, xT, Wpack);
    moe_conv_mfma<<<dim3(1792), 256, 0, stream>>>(xT, Wpack, gate_w, gate_i,
                                                  bexp, out);
}